// Round 18
// baseline (124.245 us; speedup 1.0000x reference)
//
#include <hip/hip_runtime.h>

// Problem constants (fixed by setup_inputs)
#define NB 16
#define NQ 500
#define NC 256
#define NHW 64
#define MR 8000            // B*Q rows
#define KD 9216            // GEMM1 K = 36*256

typedef float f32x4 __attribute__((ext_vector_type(4)));
typedef __bf16 bf16x8 __attribute__((ext_vector_type(8)));
typedef unsigned short ushortx8 __attribute__((ext_vector_type(8)));
typedef unsigned int uintx4 __attribute__((ext_vector_type(4)));
typedef int intx4 __attribute__((ext_vector_type(4)));

__device__ __forceinline__ unsigned short f2bf(float f) {
  unsigned int u = __builtin_bit_cast(unsigned int, f);
  u += 0x7fffu + ((u >> 16) & 1u);   // round-to-nearest-even
  return (unsigned short)(u >> 16);
}
#define U2F(u) __builtin_bit_cast(float, (unsigned int)(u))

// ---------------------------------------------------------------------------
// Kernel 1 (fused prep): grid-concatenated independent phases.
__global__ void k_prep(const float* __restrict__ mem, unsigned short* __restrict__ memb,
                       const float* __restrict__ Wk, const float* __restrict__ Wp,
                       unsigned short* __restrict__ W2s, unsigned short* __restrict__ WPs,
                       const float* __restrict__ polys, float* __restrict__ outp,
                       float* __restrict__ wsp, float* __restrict__ wts) {
  const int bid = blockIdx.x;
  if (bid < 8192) {
    size_t gid = (size_t)bid * 256 + threadIdx.x;
    const float* s = mem + gid * 8;
    f32x4 a = *(const f32x4*)s, b = *(const f32x4*)(s + 4);
    bf16x8 pk;
    pk[0] = (__bf16)a.x; pk[1] = (__bf16)a.y; pk[2] = (__bf16)a.z; pk[3] = (__bf16)a.w;
    pk[4] = (__bf16)b.x; pk[5] = (__bf16)b.y; pk[6] = (__bf16)b.z; pk[7] = (__bf16)b.w;
    *(bf16x8*)(memb + gid * 8) = pk;
  } else if (bid < 9344) {
    int tid = (bid - 8192) * 256 + threadIdx.x;  // < 294912 exactly
    int o = tid & 255;
    int th = tid >> 8;                           // 0..1151  (= t>>3)
    int r = th >> 5;                             // sample slot 0..35
    int cbase = (th & 31) * 8;
    int np = r / 9;
    int kl = r - np * 9;
    int kk = kl / 3;
    int ll = kl - kk * 3;
    const float* src = Wk + (size_t)o * KD + (size_t)(np * 256 + cbase) * 9 + kk * 3 + ll;
    ushortx8 v;
#pragma unroll
    for (int j = 0; j < 8; ++j) v[j] = f2bf(src[(size_t)j * 9]);
    *(ushortx8*)(W2s + (size_t)th * 2048 + o * 8) = v;
  } else if (bid < 9376) {
    int tid = (bid - 9344) * 256 + threadIdx.x;  // < 8192 exactly
    int o = tid & 255;
    int th = tid >> 8;
    const float* src = Wp + (size_t)o * 256 + th * 8;
    ushortx8 v;
#pragma unroll
    for (int j = 0; j < 8; ++j) v[j] = f2bf(src[j]);
    *(ushortx8*)(WPs + (size_t)th * 2048 + o * 8) = v;
  } else if (bid < 10501) {
    if (!wts) return;
    int e = (bid - 9376) * 256 + threadIdx.x;    // < 288000 exactly
    int r = e / 8000;                            // 0..35
    int n = e - r * 8000;
    int s = r & 3;
    int mm = r >> 2;
    int mdiv = (mm * 11) >> 5;                   // mm/3 for mm in [0,9)
    int mmod = mm - 3 * mdiv;
    float dhx = (1.5f * (float)mdiv - 2.0f) * 0.03125f;
    float dwy = (1.5f * (float)mmod - 2.0f) * 0.03125f;
    f32x4 ca = *(const f32x4*)(polys + (size_t)n * 8);
    f32x4 cb = *(const f32x4*)(polys + (size_t)n * 8 + 4);
    float a1 = (s == 3) ? 1.0f : (float)s * 0.33333334f;
    float a2 = a1 * a1, a3 = a2 * a1;
    float v0 = ca.x * a3 + ca.y * a2 + ca.z * a1 + ca.w;
    float v1 = cb.x * a3 + cb.y * a2 + cb.z * a1 + cb.w;
    float p0 = 2.0f * v1 - 1.0f;
    float p1 = 2.0f * v0 - 1.0f;
    const float gx = (p0 + dhx + 1.0f) * 0.5f * 63.0f;  // column
    const float gy = (p1 + dwy + 1.0f) * 0.5f * 63.0f;  // row
    const float x0f = floorf(gx), y0f = floorf(gy);
    const float fx = gx - x0f, fy = gy - y0f;
    const int ix0 = (int)x0f, iy0 = (int)y0f;
    const int ix1 = ix0 + 1, iy1 = iy0 + 1;
    const float vx0 = (ix0 >= 0 && ix0 < NHW) ? 1.0f : 0.0f;
    const float vx1 = (ix1 >= 0 && ix1 < NHW) ? 1.0f : 0.0f;
    const float vy0 = (iy0 >= 0 && iy0 < NHW) ? 1.0f : 0.0f;
    const float vy1 = (iy1 >= 0 && iy1 < NHW) ? 1.0f : 0.0f;
    const float w00 = (1.0f - fy) * (1.0f - fx) * vy0 * vx0;
    const float w01 = (1.0f - fy) * fx * vy0 * vx1;
    const float w10 = fy * (1.0f - fx) * vy1 * vx0;
    const float w11 = fy * fx * vy1 * vx1;
    const int cx0 = min(max(ix0, 0), NHW - 1), cx1 = min(max(ix1, 0), NHW - 1);
    const int cy0 = min(max(iy0, 0), NHW - 1), cy1 = min(max(iy1, 0), NHW - 1);
    float* dst = wts + (size_t)e * 8;
    f32x4 wv; wv.x = w00; wv.y = w01; wv.z = w10; wv.w = w11;
    intx4 ov;
    ov.x = (cy0 * NHW + cx0) * NC; ov.y = (cy0 * NHW + cx1) * NC;
    ov.z = (cy1 * NHW + cx0) * NC; ov.w = (cy1 * NHW + cx1) * NC;
    *(f32x4*)dst = wv;
    *(intx4*)(dst + 4) = ov;
  } else {
    int n = (bid - 10501) * 256 + threadIdx.x;
    if (n >= MR) return;
    f32x4 ca = *(const f32x4*)(polys + (size_t)n * 8);
    f32x4 cb = *(const f32x4*)(polys + (size_t)n * 8 + 4);
    const float av[4] = {0.0f, 0.33333334f, 0.66666669f, 1.0f};
#pragma unroll
    for (int s = 0; s < 4; ++s) {
      float a1 = av[s], a2 = a1 * a1, a3 = a2 * a1;
      float v0 = ca.x * a3 + ca.y * a2 + ca.z * a1 + ca.w;
      float v1 = cb.x * a3 + cb.y * a2 + cb.z * a1 + cb.w;
      float pt0 = 2.0f * v1 - 1.0f;
      float pt1 = 2.0f * v0 - 1.0f;
      outp[(size_t)n * 8 + s * 2 + 0] = pt0;
      outp[(size_t)n * 8 + s * 2 + 1] = pt1;
      wsp[(size_t)n * 8 + s * 2 + 0] = pt0;
      wsp[(size_t)n * 8 + s * 2 + 1] = pt1;
    }
  }
}

// ---------------------------------------------------------------------------
// Kernel 2: fused gather + GEMM1.
// NBUF=2: round-17 exact (64 KB dbuf A-LDS, 1 barrier/slot, 2 blocks/CU).
// NBUF=1: occupancy experiment — single 32 KB A-buffer, 2 barriers/slot,
//   36.9 KB LDS -> 4-block/CU capacity; with K=6 (768 blocks = 3/CU exact)
//   inter-block slack absorbs barrier waits (24 waves/CU vs 16).
// WTS staged via rotating 2x2KB LDS (rounds 7/15/16: allocator pins 64 VGPR
// and spills any persistent register state). Wlds hazards barrier-separated
// in both NBUF variants (write(r+1-slice)@gather(r) vs read@gather(r+1):
// >=1 barrier between; read@gather(r) vs rewrite@gather(r+1): same).
template <bool USE_WTS, int NBUF>
__global__ __launch_bounds__(512, 4) void k_gemm1(
    const unsigned short* __restrict__ memb, const float* __restrict__ pts,
    const float* __restrict__ wts, const unsigned short* __restrict__ W2s,
    const float* __restrict__ bk, float* __restrict__ PART, int K) {
  __shared__ __align__(16) unsigned short Alds[NBUF * 2048 * 8];  // 32/64 KB
  __shared__ __align__(16) float Wlds[2][512];                    // 2 x 2 KB

  const int bid = blockIdx.x;
  const int x = bid & 7;
  const int kk8 = (bid >> 3) % K;
  const int j = bid / (8 * K);
  const int t = x + 8 * j;
  if (t >= 125) return;
  const int tt = 16 * x - ((x > 5) ? (x - 5) : 0) + j;   // contiguous tile id
  const int nsl = 36 / K;
  const int r0 = kk8 * nsl;

  const int tid = threadIdx.x;
  const int n0 = tt * 64;
  const int lane = tid & 63;
  const int wave = tid >> 6;   // 0..7
  const int lr = lane & 15;
  const int ksub = lane >> 4;
  const int o0 = wave * 32;

  const int gchunk = tid & 31;
  const int gm0 = tid >> 5;    // 0..15 ; tasks handle rows gm0+16*task

  size_t boff[4];
  int nrow[4];
#pragma unroll
  for (int task = 0; task < 4; ++task) {
    nrow[task] = n0 + gm0 + 16 * task;
    boff[task] = (size_t)(nrow[task] / NQ) * (NHW * NHW * NC);
  }

  f32x4 acc[4][2] = {};

  // prologue: stage slot r0's WTS slice (2 KB) into Wlds[0]
  if (USE_WTS) {
    if (tid < 128) {
      f32x4 v = *(const f32x4*)(wts + ((size_t)r0 * 8000 + n0) * 8 + tid * 4);
      *(f32x4*)(&Wlds[0][tid * 4]) = v;
    }
    __syncthreads();
  }

  for (int r = r0; r < r0 + nsl; ++r) {
    const int lbase = (NBUF == 2) ? ((r - r0) & 1) * 2048 : 0;  // A-LDS select
    const int cur = (r - r0) & 1;              // WTS LDS buffer select
    const int nbuf = cur ^ 1;
    const int rn = (r + 1 < 35) ? (r + 1) : 35;
    // NBUF=1: barrier_A protects A-LDS reuse (prev mfma reads done)
    if (NBUF == 1 && r != r0) __syncthreads();
    float dhx = 0.0f, dwy = 0.0f;
    int s = 0;
    if (!USE_WTS) {
      s = r & 3;
      const int mm = r >> 2;
      const int mdiv = (mm * 11) >> 5;
      const int mmod = mm - 3 * mdiv;
      dhx = (1.5f * (float)mdiv - 2.0f) * 0.03125f;
      dwy = (1.5f * (float)mmod - 2.0f) * 0.03125f;
    } else {
      if (tid < 128) {
        f32x4 v = *(const f32x4*)(wts + ((size_t)rn * 8000 + n0) * 8 + tid * 4);
        *(f32x4*)(&Wlds[nbuf][tid * 4]) = v;
      }
    }
#pragma unroll 2
    for (int task = 0; task < 4; ++task) {
      const int m = gm0 + task * 16;
      const int n = nrow[task];
      float w00, w01, w10, w11;
      int o00, o01, o10, o11;
      if (USE_WTS) {
        const float* we = &Wlds[cur][(gm0 + 16 * task) * 8];
        f32x4 wv = *(const f32x4*)we;
        intx4 ov = *(const intx4*)(we + 4);
        w00 = wv.x; w01 = wv.y; w10 = wv.z; w11 = wv.w;
        o00 = ov.x; o01 = ov.y; o10 = ov.z; o11 = ov.w;
      } else {
        const float p0 = pts[(size_t)n * 8 + s * 2 + 0];
        const float p1 = pts[(size_t)n * 8 + s * 2 + 1];
        const float gx = (p0 + dhx + 1.0f) * 0.5f * 63.0f;  // column
        const float gy = (p1 + dwy + 1.0f) * 0.5f * 63.0f;  // row
        const float x0f = floorf(gx), y0f = floorf(gy);
        const float fx = gx - x0f, fy = gy - y0f;
        const int ix0 = (int)x0f, iy0 = (int)y0f;
        const int ix1 = ix0 + 1, iy1 = iy0 + 1;
        const float vx0 = (ix0 >= 0 && ix0 < NHW) ? 1.0f : 0.0f;
        const float vx1 = (ix1 >= 0 && ix1 < NHW) ? 1.0f : 0.0f;
        const float vy0 = (iy0 >= 0 && iy0 < NHW) ? 1.0f : 0.0f;
        const float vy1 = (iy1 >= 0 && iy1 < NHW) ? 1.0f : 0.0f;
        w00 = (1.0f - fy) * (1.0f - fx) * vy0 * vx0;
        w01 = (1.0f - fy) * fx * vy0 * vx1;
        w10 = fy * (1.0f - fx) * vy1 * vx0;
        w11 = fy * fx * vy1 * vx1;
        const int cx0 = min(max(ix0, 0), NHW - 1), cx1 = min(max(ix1, 0), NHW - 1);
        const int cy0 = min(max(iy0, 0), NHW - 1), cy1 = min(max(iy1, 0), NHW - 1);
        o00 = (cy0 * NHW + cx0) * NC; o01 = (cy0 * NHW + cx1) * NC;
        o10 = (cy1 * NHW + cx0) * NC; o11 = (cy1 * NHW + cx1) * NC;
      }
      const unsigned short* mb = memb + boff[task] + gchunk * 8;
      uintx4 u00 = *(const uintx4*)(mb + o00);
      uintx4 u01 = *(const uintx4*)(mb + o01);
      uintx4 u10 = *(const uintx4*)(mb + o10);
      uintx4 u11 = *(const uintx4*)(mb + o11);
      f32x4 a00, b00, a01, b01, a10, b10, a11, b11;
      a00.x = U2F(u00.x << 16); a00.y = U2F(u00.x & 0xFFFF0000u);
      a00.z = U2F(u00.y << 16); a00.w = U2F(u00.y & 0xFFFF0000u);
      b00.x = U2F(u00.z << 16); b00.y = U2F(u00.z & 0xFFFF0000u);
      b00.z = U2F(u00.w << 16); b00.w = U2F(u00.w & 0xFFFF0000u);
      a01.x = U2F(u01.x << 16); a01.y = U2F(u01.x & 0xFFFF0000u);
      a01.z = U2F(u01.y << 16); a01.w = U2F(u01.y & 0xFFFF0000u);
      b01.x = U2F(u01.z << 16); b01.y = U2F(u01.z & 0xFFFF0000u);
      b01.z = U2F(u01.w << 16); b01.w = U2F(u01.w & 0xFFFF0000u);
      a10.x = U2F(u10.x << 16); a10.y = U2F(u10.x & 0xFFFF0000u);
      a10.z = U2F(u10.y << 16); a10.w = U2F(u10.y & 0xFFFF0000u);
      b10.x = U2F(u10.z << 16); b10.y = U2F(u10.z & 0xFFFF0000u);
      b10.z = U2F(u10.w << 16); b10.w = U2F(u10.w & 0xFFFF0000u);
      a11.x = U2F(u11.x << 16); a11.y = U2F(u11.x & 0xFFFF0000u);
      a11.z = U2F(u11.y << 16); a11.w = U2F(u11.y & 0xFFFF0000u);
      b11.x = U2F(u11.z << 16); b11.y = U2F(u11.z & 0xFFFF0000u);
      b11.z = U2F(u11.w << 16); b11.w = U2F(u11.w & 0xFFFF0000u);
      f32x4 ra = a00 * w00 + a01 * w01 + a10 * w10 + a11 * w11;
      f32x4 rb = b00 * w00 + b01 * w01 + b10 * w10 + b11 * w11;
      bf16x8 pk;
      pk[0] = (__bf16)ra.x; pk[1] = (__bf16)ra.y;
      pk[2] = (__bf16)ra.z; pk[3] = (__bf16)ra.w;
      pk[4] = (__bf16)rb.x; pk[5] = (__bf16)rb.y;
      pk[6] = (__bf16)rb.z; pk[7] = (__bf16)rb.w;
      const int slot = lbase + gchunk * 64 + (m ^ (gchunk & 15));
      *(bf16x8*)(Alds + slot * 8) = pk;
    }
    __syncthreads();
    const size_t rbase = (size_t)r * 32;
#pragma unroll
    for (int kstep = 0; kstep < 8; ++kstep) {
      const int chunk = kstep * 4 + ksub;
      const unsigned short* bp = W2s + (rbase + chunk) * 2048 + (o0 + lr) * 8;
      ushortx8 ub0 = *(const ushortx8*)bp;
      ushortx8 ub1 = *(const ushortx8*)(bp + 128);
      bf16x8 fb0 = __builtin_bit_cast(bf16x8, ub0);
      bf16x8 fb1 = __builtin_bit_cast(bf16x8, ub1);
#pragma unroll
      for (int mf = 0; mf < 4; ++mf) {
        const int sa = lbase + chunk * 64 + ((mf * 16 + lr) ^ (chunk & 15));
        ushortx8 ua = *(const ushortx8*)(Alds + sa * 8);
        bf16x8 fa = __builtin_bit_cast(bf16x8, ua);
        acc[mf][0] = __builtin_amdgcn_mfma_f32_16x16x32_bf16(fa, fb0, acc[mf][0], 0, 0, 0);
        acc[mf][1] = __builtin_amdgcn_mfma_f32_16x16x32_bf16(fa, fb1, acc[mf][1], 0, 0, 0);
      }
    }
  }
  // epilogue: fp32 partials. C/D: col=lane&15, row=(lane>>4)*4+reg
  float* dst = PART + (size_t)kk8 * (MR * NC);
#pragma unroll
  for (int mf = 0; mf < 4; ++mf)
#pragma unroll
    for (int nf = 0; nf < 2; ++nf) {
      const int o = o0 + nf * 16 + lr;
#pragma unroll
      for (int reg = 0; reg < 4; ++reg) {
        const int mrow = mf * 16 + ksub * 4 + reg;
        dst[(size_t)(n0 + mrow) * 256 + o] = acc[mf][nf][reg];
      }
    }
}

// ---------------------------------------------------------------------------
// Kernel 3: fused reduce + GEMM2 (16-row tiles). Runtime-K partial sum
// (pointer arithmetic only — no rule-20 hazard), +bk, relu, native bf16 cast.
__global__ __launch_bounds__(256) void k_gemm2(
    const float* __restrict__ PART, const float* __restrict__ bk,
    const unsigned short* __restrict__ WPs, const float* __restrict__ bp,
    float* __restrict__ outc, int K) {
  const int tid = threadIdx.x;
  const int n0 = blockIdx.x * 16;
  const int lane = tid & 63;
  const int wave = tid >> 6;  // 0..3
  const int lr = lane & 15;
  const int ksub = lane >> 4;
  const int o0 = wave * 64;
  f32x4 acc[4] = {};
#pragma unroll
  for (int kstep = 0; kstep < 8; ++kstep) {
    const int t0 = kstep * 32 + ksub * 8;
    const float* base = PART + (size_t)(n0 + lr) * 256 + t0;
    f32x4 s0 = *(const f32x4*)base;
    f32x4 s1 = *(const f32x4*)(base + 4);
    for (int k = 1; k < K; ++k) {
      const float* pk_ = base + (size_t)k * (MR * NC);
      s0 += *(const f32x4*)pk_;
      s1 += *(const f32x4*)(pk_ + 4);
    }
    s0 += *(const f32x4*)(bk + t0);
    s1 += *(const f32x4*)(bk + t0 + 4);
    bf16x8 fa;
#pragma unroll
    for (int e = 0; e < 4; ++e) {
      float v0 = s0[e] > 0.0f ? s0[e] : 0.0f;
      float v1 = s1[e] > 0.0f ? s1[e] : 0.0f;
      fa[e] = (__bf16)v0;
      fa[e + 4] = (__bf16)v1;
    }
    const int chunk = kstep * 4 + ksub;
#pragma unroll
    for (int nf = 0; nf < 4; ++nf) {
      ushortx8 ub = *(const ushortx8*)(WPs + (size_t)chunk * 2048 + (o0 + nf * 16 + lr) * 8);
      bf16x8 fb = __builtin_bit_cast(bf16x8, ub);
      acc[nf] = __builtin_amdgcn_mfma_f32_16x16x32_bf16(fa, fb, acc[nf], 0, 0, 0);
    }
  }
#pragma unroll
  for (int nf = 0; nf < 4; ++nf) {
    const int o = o0 + nf * 16 + lr;
    const float bpo = bp[o];
#pragma unroll
    for (int reg = 0; reg < 4; ++reg) {
      const int mrow = ksub * 4 + reg;
      outc[(size_t)(n0 + mrow) * 256 + o] = acc[nf][reg] + bpo;
    }
  }
}

// ---------------------------------------------------------------------------
extern "C" void kernel_launch(void* const* d_in, const int* in_sizes, int n_in,
                              void* d_out, int out_size, void* d_ws, size_t ws_size,
                              hipStream_t stream) {
  (void)in_sizes; (void)n_in; (void)out_size;
  const float* polys = (const float*)d_in[1];
  const float* mem   = (const float*)d_in[2];
  const float* Wk    = (const float*)d_in[4];
  const float* bk    = (const float*)d_in[5];
  const float* Wp    = (const float*)d_in[6];
  const float* bp    = (const float*)d_in[7];
  float* out = (float*)d_out;
  float* out_pts = out + (size_t)MR * NC;   // second output: points

  // ws layout: base block, then [WTS?] + MEMB + PART (K x PART_SZ)
  unsigned short* W2s = (unsigned short*)d_ws;                       // 4,718,592 B
  unsigned short* WPs = (unsigned short*)((char*)d_ws + 4718592);    //   131,072 B
  float*          PTS = (float*)((char*)d_ws + 4849664);             //   256,000 B
  const size_t BASE_END = 9201664;
  const size_t WTS_SZ  = 9216000ull;      // 288000 * 32 B
  const size_t MEMB_SZ = 33554432ull;     // 16*4096*256 bf16
  const size_t PART_SZ = 8192000ull;      // 8000*256 fp32 per split

  bool use_wts = (ws_size >= BASE_END + WTS_SZ + MEMB_SZ + 4 * PART_SZ);
  bool k6 = use_wts && (ws_size >= BASE_END + WTS_SZ + MEMB_SZ + 6 * PART_SZ);
  int K = k6 ? 6 : 4;
  size_t memb_off = use_wts ? (BASE_END + WTS_SZ) : BASE_END;
  float*          WTS  = use_wts ? (float*)((char*)d_ws + BASE_END) : nullptr;
  unsigned short* MEMB = (unsigned short*)((char*)d_ws + memb_off);
  float*          PART = (float*)((char*)d_ws + memb_off + MEMB_SZ);

  hipLaunchKernelGGL(k_prep, dim3(10533), dim3(256), 0, stream,
                     mem, MEMB, Wk, Wp, W2s, WPs, polys, out_pts, PTS, WTS);
  if (k6)
    hipLaunchKernelGGL((k_gemm1<true, 1>), dim3(128 * 6), dim3(512), 0, stream,
                       MEMB, PTS, WTS, W2s, bk, PART, 6);
  else if (use_wts)
    hipLaunchKernelGGL((k_gemm1<true, 2>), dim3(128 * 4), dim3(512), 0, stream,
                       MEMB, PTS, WTS, W2s, bk, PART, 4);
  else
    hipLaunchKernelGGL((k_gemm1<false, 2>), dim3(128 * 4), dim3(512), 0, stream,
                       MEMB, PTS, WTS, W2s, bk, PART, 4);
  hipLaunchKernelGGL(k_gemm2, dim3(500), dim3(256), 0, stream, PART, bk, WPs, bp, out, K);
}

// Round 19
// 104.779 us; speedup vs baseline: 1.1858x; 1.1858x over previous
//
#include <hip/hip_runtime.h>

// Problem constants (fixed by setup_inputs)
#define NB 16
#define NQ 500
#define NC 256
#define NHW 64
#define MR 8000            // B*Q rows
#define KD 9216            // GEMM1 K = 36*256

typedef float f32x4 __attribute__((ext_vector_type(4)));
typedef __bf16 bf16x8 __attribute__((ext_vector_type(8)));
typedef unsigned short ushortx8 __attribute__((ext_vector_type(8)));
typedef unsigned int uintx4 __attribute__((ext_vector_type(4)));
typedef int intx4 __attribute__((ext_vector_type(4)));

__device__ __forceinline__ unsigned short f2bf(float f) {
  unsigned int u = __builtin_bit_cast(unsigned int, f);
  u += 0x7fffu + ((u >> 16) & 1u);   // round-to-nearest-even
  return (unsigned short)(u >> 16);
}
#define U2F(u) __builtin_bit_cast(float, (unsigned int)(u))

// ---------------------------------------------------------------------------
// Kernel 1 (fused prep): grid-concatenated independent phases.
__global__ void k_prep(const float* __restrict__ mem, unsigned short* __restrict__ memb,
                       const float* __restrict__ Wk, const float* __restrict__ Wp,
                       unsigned short* __restrict__ W2s, unsigned short* __restrict__ WPs,
                       const float* __restrict__ polys, float* __restrict__ outp,
                       float* __restrict__ wsp, float* __restrict__ wts) {
  const int bid = blockIdx.x;
  if (bid < 8192) {
    size_t gid = (size_t)bid * 256 + threadIdx.x;
    const float* s = mem + gid * 8;
    f32x4 a = *(const f32x4*)s, b = *(const f32x4*)(s + 4);
    bf16x8 pk;
    pk[0] = (__bf16)a.x; pk[1] = (__bf16)a.y; pk[2] = (__bf16)a.z; pk[3] = (__bf16)a.w;
    pk[4] = (__bf16)b.x; pk[5] = (__bf16)b.y; pk[6] = (__bf16)b.z; pk[7] = (__bf16)b.w;
    *(bf16x8*)(memb + gid * 8) = pk;
  } else if (bid < 9344) {
    int tid = (bid - 8192) * 256 + threadIdx.x;  // < 294912 exactly
    int o = tid & 255;
    int th = tid >> 8;                           // 0..1151  (= t>>3)
    int r = th >> 5;                             // sample slot 0..35
    int cbase = (th & 31) * 8;
    int np = r / 9;
    int kl = r - np * 9;
    int kk = kl / 3;
    int ll = kl - kk * 3;
    const float* src = Wk + (size_t)o * KD + (size_t)(np * 256 + cbase) * 9 + kk * 3 + ll;
    ushortx8 v;
#pragma unroll
    for (int j = 0; j < 8; ++j) v[j] = f2bf(src[(size_t)j * 9]);
    *(ushortx8*)(W2s + (size_t)th * 2048 + o * 8) = v;
  } else if (bid < 9376) {
    int tid = (bid - 9344) * 256 + threadIdx.x;  // < 8192 exactly
    int o = tid & 255;
    int th = tid >> 8;
    const float* src = Wp + (size_t)o * 256 + th * 8;
    ushortx8 v;
#pragma unroll
    for (int j = 0; j < 8; ++j) v[j] = f2bf(src[j]);
    *(ushortx8*)(WPs + (size_t)th * 2048 + o * 8) = v;
  } else if (bid < 10501) {
    if (!wts) return;
    int e = (bid - 9376) * 256 + threadIdx.x;    // < 288000 exactly
    int r = e / 8000;                            // 0..35
    int n = e - r * 8000;
    int s = r & 3;
    int mm = r >> 2;
    int mdiv = (mm * 11) >> 5;                   // mm/3 for mm in [0,9)
    int mmod = mm - 3 * mdiv;
    float dhx = (1.5f * (float)mdiv - 2.0f) * 0.03125f;
    float dwy = (1.5f * (float)mmod - 2.0f) * 0.03125f;
    f32x4 ca = *(const f32x4*)(polys + (size_t)n * 8);
    f32x4 cb = *(const f32x4*)(polys + (size_t)n * 8 + 4);
    float a1 = (s == 3) ? 1.0f : (float)s * 0.33333334f;
    float a2 = a1 * a1, a3 = a2 * a1;
    float v0 = ca.x * a3 + ca.y * a2 + ca.z * a1 + ca.w;
    float v1 = cb.x * a3 + cb.y * a2 + cb.z * a1 + cb.w;
    float p0 = 2.0f * v1 - 1.0f;
    float p1 = 2.0f * v0 - 1.0f;
    const float gx = (p0 + dhx + 1.0f) * 0.5f * 63.0f;  // column
    const float gy = (p1 + dwy + 1.0f) * 0.5f * 63.0f;  // row
    const float x0f = floorf(gx), y0f = floorf(gy);
    const float fx = gx - x0f, fy = gy - y0f;
    const int ix0 = (int)x0f, iy0 = (int)y0f;
    const int ix1 = ix0 + 1, iy1 = iy0 + 1;
    const float vx0 = (ix0 >= 0 && ix0 < NHW) ? 1.0f : 0.0f;
    const float vx1 = (ix1 >= 0 && ix1 < NHW) ? 1.0f : 0.0f;
    const float vy0 = (iy0 >= 0 && iy0 < NHW) ? 1.0f : 0.0f;
    const float vy1 = (iy1 >= 0 && iy1 < NHW) ? 1.0f : 0.0f;
    const float w00 = (1.0f - fy) * (1.0f - fx) * vy0 * vx0;
    const float w01 = (1.0f - fy) * fx * vy0 * vx1;
    const float w10 = fy * (1.0f - fx) * vy1 * vx0;
    const float w11 = fy * fx * vy1 * vx1;
    const int cx0 = min(max(ix0, 0), NHW - 1), cx1 = min(max(ix1, 0), NHW - 1);
    const int cy0 = min(max(iy0, 0), NHW - 1), cy1 = min(max(iy1, 0), NHW - 1);
    float* dst = wts + (size_t)e * 8;
    f32x4 wv; wv.x = w00; wv.y = w01; wv.z = w10; wv.w = w11;
    intx4 ov;
    ov.x = (cy0 * NHW + cx0) * NC; ov.y = (cy0 * NHW + cx1) * NC;
    ov.z = (cy1 * NHW + cx0) * NC; ov.w = (cy1 * NHW + cx1) * NC;
    *(f32x4*)dst = wv;
    *(intx4*)(dst + 4) = ov;
  } else {
    int n = (bid - 10501) * 256 + threadIdx.x;
    if (n >= MR) return;
    f32x4 ca = *(const f32x4*)(polys + (size_t)n * 8);
    f32x4 cb = *(const f32x4*)(polys + (size_t)n * 8 + 4);
    const float av[4] = {0.0f, 0.33333334f, 0.66666669f, 1.0f};
#pragma unroll
    for (int s = 0; s < 4; ++s) {
      float a1 = av[s], a2 = a1 * a1, a3 = a2 * a1;
      float v0 = ca.x * a3 + ca.y * a2 + ca.z * a1 + ca.w;
      float v1 = cb.x * a3 + cb.y * a2 + cb.z * a1 + cb.w;
      float pt0 = 2.0f * v1 - 1.0f;
      float pt1 = 2.0f * v0 - 1.0f;
      outp[(size_t)n * 8 + s * 2 + 0] = pt0;
      outp[(size_t)n * 8 + s * 2 + 1] = pt1;
      wsp[(size_t)n * 8 + s * 2 + 0] = pt0;
      wsp[(size_t)n * 8 + s * 2 + 1] = pt1;
    }
  }
}

// ---------------------------------------------------------------------------
// Kernel 2: fused gather + GEMM1. ROUND-17 VERIFIED OPTIMUM (70.8 us):
// K=4, M=64 tile, 64 KB dbuf A-LDS, ONE barrier/slot, launch_bounds(512,4),
// WTS staged via rotating 2x2KB LDS buffer.
// Closed levers (measured): register prefetch (rounds 7/15/16: allocator pins
// 64 VGPR, spills any persistent state); occupancy via single-buffer/more
// blocks (rounds 8/9/18: 2-barrier structure loses 12-18%); VALU
// hand-vectorization (round 14: compiler already optimal).
template <bool USE_WTS>
__global__ __launch_bounds__(512, 4) void k_gemm1(
    const unsigned short* __restrict__ memb, const float* __restrict__ pts,
    const float* __restrict__ wts, const unsigned short* __restrict__ W2s,
    const float* __restrict__ bk, float* __restrict__ PART, int K) {
  __shared__ __align__(16) unsigned short Alds[2 * 2048 * 8];  // 64 KB
  __shared__ __align__(16) float Wlds[2][512];                 // 2 x 2 KB

  const int bid = blockIdx.x;
  const int x = bid & 7;
  const int kk8 = (bid >> 3) % K;
  const int j = bid / (8 * K);
  const int t = x + 8 * j;
  if (t >= 125) return;
  const int tt = 16 * x - ((x > 5) ? (x - 5) : 0) + j;   // contiguous tile id
  const int nsl = 36 / K;
  const int r0 = kk8 * nsl;

  const int tid = threadIdx.x;
  const int n0 = tt * 64;
  const int lane = tid & 63;
  const int wave = tid >> 6;   // 0..7
  const int lr = lane & 15;
  const int ksub = lane >> 4;
  const int o0 = wave * 32;

  const int gchunk = tid & 31;
  const int gm0 = tid >> 5;    // 0..15 ; tasks handle rows gm0+16*task

  size_t boff[4];
  int nrow[4];
#pragma unroll
  for (int task = 0; task < 4; ++task) {
    nrow[task] = n0 + gm0 + 16 * task;
    boff[task] = (size_t)(nrow[task] / NQ) * (NHW * NHW * NC);
  }

  f32x4 acc[4][2] = {};

  // prologue: stage slot r0's WTS slice (2 KB) into Wlds[0]
  if (USE_WTS) {
    if (tid < 128) {
      f32x4 v = *(const f32x4*)(wts + ((size_t)r0 * 8000 + n0) * 8 + tid * 4);
      *(f32x4*)(&Wlds[0][tid * 4]) = v;
    }
    __syncthreads();
  }

  for (int r = r0; r < r0 + nsl; ++r) {
    const int lbase = ((r - r0) & 1) * 2048;   // A-LDS buffer select
    const int cur = (r - r0) & 1;              // WTS LDS buffer select
    const int nbuf = cur ^ 1;
    const int rn = (r + 1 < 35) ? (r + 1) : 35;  // next-slot stage (clamped;
                                                 // final iteration's is unused)
    float dhx = 0.0f, dwy = 0.0f;
    int s = 0;
    if (!USE_WTS) {
      s = r & 3;
      const int mm = r >> 2;
      const int mdiv = (mm * 11) >> 5;
      const int mmod = mm - 3 * mdiv;
      dhx = (1.5f * (float)mdiv - 2.0f) * 0.03125f;
      dwy = (1.5f * (float)mmod - 2.0f) * 0.03125f;
    } else {
      // stage slot r+1's WTS slice early: global load overlaps the 4 task
      // bodies; ds_write lands before this slot's barrier.
      if (tid < 128) {
        f32x4 v = *(const f32x4*)(wts + ((size_t)rn * 8000 + n0) * 8 + tid * 4);
        *(f32x4*)(&Wlds[nbuf][tid * 4]) = v;
      }
    }
#pragma unroll 2
    for (int task = 0; task < 4; ++task) {
      const int m = gm0 + task * 16;
      const int n = nrow[task];
      float w00, w01, w10, w11;
      int o00, o01, o10, o11;
      if (USE_WTS) {
        const float* we = &Wlds[cur][(gm0 + 16 * task) * 8];
        f32x4 wv = *(const f32x4*)we;
        intx4 ov = *(const intx4*)(we + 4);
        w00 = wv.x; w01 = wv.y; w10 = wv.z; w11 = wv.w;
        o00 = ov.x; o01 = ov.y; o10 = ov.z; o11 = ov.w;
      } else {
        const float p0 = pts[(size_t)n * 8 + s * 2 + 0];
        const float p1 = pts[(size_t)n * 8 + s * 2 + 1];
        const float gx = (p0 + dhx + 1.0f) * 0.5f * 63.0f;  // column
        const float gy = (p1 + dwy + 1.0f) * 0.5f * 63.0f;  // row
        const float x0f = floorf(gx), y0f = floorf(gy);
        const float fx = gx - x0f, fy = gy - y0f;
        const int ix0 = (int)x0f, iy0 = (int)y0f;
        const int ix1 = ix0 + 1, iy1 = iy0 + 1;
        const float vx0 = (ix0 >= 0 && ix0 < NHW) ? 1.0f : 0.0f;
        const float vx1 = (ix1 >= 0 && ix1 < NHW) ? 1.0f : 0.0f;
        const float vy0 = (iy0 >= 0 && iy0 < NHW) ? 1.0f : 0.0f;
        const float vy1 = (iy1 >= 0 && iy1 < NHW) ? 1.0f : 0.0f;
        w00 = (1.0f - fy) * (1.0f - fx) * vy0 * vx0;
        w01 = (1.0f - fy) * fx * vy0 * vx1;
        w10 = fy * (1.0f - fx) * vy1 * vx0;
        w11 = fy * fx * vy1 * vx1;
        const int cx0 = min(max(ix0, 0), NHW - 1), cx1 = min(max(ix1, 0), NHW - 1);
        const int cy0 = min(max(iy0, 0), NHW - 1), cy1 = min(max(iy1, 0), NHW - 1);
        o00 = (cy0 * NHW + cx0) * NC; o01 = (cy0 * NHW + cx1) * NC;
        o10 = (cy1 * NHW + cx0) * NC; o11 = (cy1 * NHW + cx1) * NC;
      }
      const unsigned short* mb = memb + boff[task] + gchunk * 8;
      uintx4 u00 = *(const uintx4*)(mb + o00);
      uintx4 u01 = *(const uintx4*)(mb + o01);
      uintx4 u10 = *(const uintx4*)(mb + o10);
      uintx4 u11 = *(const uintx4*)(mb + o11);
      // expand: word w holds elems {2w (lo), 2w+1 (hi)}; ra <- elems 0..3,
      // rb <- elems 4..7
      f32x4 a00, b00, a01, b01, a10, b10, a11, b11;
      a00.x = U2F(u00.x << 16); a00.y = U2F(u00.x & 0xFFFF0000u);
      a00.z = U2F(u00.y << 16); a00.w = U2F(u00.y & 0xFFFF0000u);
      b00.x = U2F(u00.z << 16); b00.y = U2F(u00.z & 0xFFFF0000u);
      b00.z = U2F(u00.w << 16); b00.w = U2F(u00.w & 0xFFFF0000u);
      a01.x = U2F(u01.x << 16); a01.y = U2F(u01.x & 0xFFFF0000u);
      a01.z = U2F(u01.y << 16); a01.w = U2F(u01.y & 0xFFFF0000u);
      b01.x = U2F(u01.z << 16); b01.y = U2F(u01.z & 0xFFFF0000u);
      b01.z = U2F(u01.w << 16); b01.w = U2F(u01.w & 0xFFFF0000u);
      a10.x = U2F(u10.x << 16); a10.y = U2F(u10.x & 0xFFFF0000u);
      a10.z = U2F(u10.y << 16); a10.w = U2F(u10.y & 0xFFFF0000u);
      b10.x = U2F(u10.z << 16); b10.y = U2F(u10.z & 0xFFFF0000u);
      b10.z = U2F(u10.w << 16); b10.w = U2F(u10.w & 0xFFFF0000u);
      a11.x = U2F(u11.x << 16); a11.y = U2F(u11.x & 0xFFFF0000u);
      a11.z = U2F(u11.y << 16); a11.w = U2F(u11.y & 0xFFFF0000u);
      b11.x = U2F(u11.z << 16); b11.y = U2F(u11.z & 0xFFFF0000u);
      b11.z = U2F(u11.w << 16); b11.w = U2F(u11.w & 0xFFFF0000u);
      f32x4 ra = a00 * w00 + a01 * w01 + a10 * w10 + a11 * w11;
      f32x4 rb = b00 * w00 + b01 * w01 + b10 * w10 + b11 * w11;
      bf16x8 pk;
      pk[0] = (__bf16)ra.x; pk[1] = (__bf16)ra.y;
      pk[2] = (__bf16)ra.z; pk[3] = (__bf16)ra.w;
      pk[4] = (__bf16)rb.x; pk[5] = (__bf16)rb.y;
      pk[6] = (__bf16)rb.z; pk[7] = (__bf16)rb.w;
      const int slot = lbase + gchunk * 64 + (m ^ (gchunk & 15));
      *(bf16x8*)(Alds + slot * 8) = pk;
    }
    __syncthreads();
    const size_t rbase = (size_t)r * 32;
#pragma unroll
    for (int kstep = 0; kstep < 8; ++kstep) {
      const int chunk = kstep * 4 + ksub;
      const unsigned short* bp = W2s + (rbase + chunk) * 2048 + (o0 + lr) * 8;
      ushortx8 ub0 = *(const ushortx8*)bp;
      ushortx8 ub1 = *(const ushortx8*)(bp + 128);
      bf16x8 fb0 = __builtin_bit_cast(bf16x8, ub0);
      bf16x8 fb1 = __builtin_bit_cast(bf16x8, ub1);
#pragma unroll
      for (int mf = 0; mf < 4; ++mf) {
        const int sa = lbase + chunk * 64 + ((mf * 16 + lr) ^ (chunk & 15));
        ushortx8 ua = *(const ushortx8*)(Alds + sa * 8);
        bf16x8 fa = __builtin_bit_cast(bf16x8, ua);
        acc[mf][0] = __builtin_amdgcn_mfma_f32_16x16x32_bf16(fa, fb0, acc[mf][0], 0, 0, 0);
        acc[mf][1] = __builtin_amdgcn_mfma_f32_16x16x32_bf16(fa, fb1, acc[mf][1], 0, 0, 0);
      }
    }
  }
  // epilogue: fp32 partials. C/D: col=lane&15, row=(lane>>4)*4+reg
  float* dst = PART + (size_t)kk8 * (MR * NC);
#pragma unroll
  for (int mf = 0; mf < 4; ++mf)
#pragma unroll
    for (int nf = 0; nf < 2; ++nf) {
      const int o = o0 + nf * 16 + lr;
#pragma unroll
      for (int reg = 0; reg < 4; ++reg) {
        const int mrow = mf * 16 + ksub * 4 + reg;
        dst[(size_t)(n0 + mrow) * 256 + o] = acc[mf][nf][reg];
      }
    }
}

// ---------------------------------------------------------------------------
// Kernel 3: fused reduce + GEMM2 (16-row tiles).
// A-fragment built in-register: sum 4 PART slices, +bk, relu, native bf16 cast
// (== k_red's f2bf, verified). Same sum order k=0..3 as k_red => bit-identical.
__global__ __launch_bounds__(256) void k_gemm2(
    const float* __restrict__ PART, const float* __restrict__ bk,
    const unsigned short* __restrict__ WPs, const float* __restrict__ bp,
    float* __restrict__ outc) {
  const int tid = threadIdx.x;
  const int n0 = blockIdx.x * 16;
  const int lane = tid & 63;
  const int wave = tid >> 6;  // 0..3
  const int lr = lane & 15;
  const int ksub = lane >> 4;
  const int o0 = wave * 64;
  f32x4 acc[4] = {};
#pragma unroll
  for (int kstep = 0; kstep < 8; ++kstep) {
    const int t0 = kstep * 32 + ksub * 8;
    const float* base = PART + (size_t)(n0 + lr) * 256 + t0;
    f32x4 s0 = *(const f32x4*)base;
    f32x4 s1 = *(const f32x4*)(base + 4);
#pragma unroll
    for (int k = 1; k < 4; ++k) {
      const float* pk_ = base + (size_t)k * (MR * NC);
      s0 += *(const f32x4*)pk_;
      s1 += *(const f32x4*)(pk_ + 4);
    }
    s0 += *(const f32x4*)(bk + t0);
    s1 += *(const f32x4*)(bk + t0 + 4);
    bf16x8 fa;
#pragma unroll
    for (int e = 0; e < 4; ++e) {
      float v0 = s0[e] > 0.0f ? s0[e] : 0.0f;
      float v1 = s1[e] > 0.0f ? s1[e] : 0.0f;
      fa[e] = (__bf16)v0;
      fa[e + 4] = (__bf16)v1;
    }
    const int chunk = kstep * 4 + ksub;
#pragma unroll
    for (int nf = 0; nf < 4; ++nf) {
      ushortx8 ub = *(const ushortx8*)(WPs + (size_t)chunk * 2048 + (o0 + nf * 16 + lr) * 8);
      bf16x8 fb = __builtin_bit_cast(bf16x8, ub);
      acc[nf] = __builtin_amdgcn_mfma_f32_16x16x32_bf16(fa, fb, acc[nf], 0, 0, 0);
    }
  }
#pragma unroll
  for (int nf = 0; nf < 4; ++nf) {
    const int o = o0 + nf * 16 + lr;
    const float bpo = bp[o];
#pragma unroll
    for (int reg = 0; reg < 4; ++reg) {
      const int mrow = ksub * 4 + reg;
      outc[(size_t)(n0 + mrow) * 256 + o] = acc[nf][reg] + bpo;
    }
  }
}

// ---------------------------------------------------------------------------
extern "C" void kernel_launch(void* const* d_in, const int* in_sizes, int n_in,
                              void* d_out, int out_size, void* d_ws, size_t ws_size,
                              hipStream_t stream) {
  (void)in_sizes; (void)n_in; (void)out_size;
  const float* polys = (const float*)d_in[1];
  const float* mem   = (const float*)d_in[2];
  const float* Wk    = (const float*)d_in[4];
  const float* bk    = (const float*)d_in[5];
  const float* Wp    = (const float*)d_in[6];
  const float* bp    = (const float*)d_in[7];
  float* out = (float*)d_out;
  float* out_pts = out + (size_t)MR * NC;   // second output: points

  // ws layout: base block, then [WTS?] + MEMB + PART (K=4)
  unsigned short* W2s = (unsigned short*)d_ws;                       // 4,718,592 B
  unsigned short* WPs = (unsigned short*)((char*)d_ws + 4718592);    //   131,072 B
  float*          PTS = (float*)((char*)d_ws + 4849664);             //   256,000 B
  const size_t BASE_END = 9201664;
  const size_t WTS_SZ  = 9216000ull;      // 288000 * 32 B
  const size_t MEMB_SZ = 33554432ull;     // 16*4096*256 bf16
  const size_t PART_SZ = 8192000ull;      // 8000*256 fp32 per split
  const int K = 4;

  bool use_wts = (ws_size >= BASE_END + WTS_SZ + MEMB_SZ + 4 * PART_SZ);
  size_t memb_off = use_wts ? (BASE_END + WTS_SZ) : BASE_END;
  float*          WTS  = use_wts ? (float*)((char*)d_ws + BASE_END) : nullptr;
  unsigned short* MEMB = (unsigned short*)((char*)d_ws + memb_off);
  float*          PART = (float*)((char*)d_ws + memb_off + MEMB_SZ);

  hipLaunchKernelGGL(k_prep, dim3(10533), dim3(256), 0, stream,
                     mem, MEMB, Wk, Wp, W2s, WPs, polys, out_pts, PTS, WTS);
  if (use_wts)
    hipLaunchKernelGGL(k_gemm1<true>, dim3(128 * K), dim3(512), 0, stream,
                       MEMB, PTS, WTS, W2s, bk, PART, K);
  else
    hipLaunchKernelGGL(k_gemm1<false>, dim3(128 * K), dim3(512), 0, stream,
                       MEMB, PTS, WTS, W2s, bk, PART, K);
  hipLaunchKernelGGL(k_gemm2, dim3(500), dim3(256), 0, stream, PART, bk, WPs, bp, out);
}

// Round 20
// 104.777 us; speedup vs baseline: 1.1858x; 1.0000x over previous
//
#include <hip/hip_runtime.h>

// Problem constants (fixed by setup_inputs)
#define NB 16
#define NQ 500
#define NC 256
#define NHW 64
#define MR 8000            // B*Q rows
#define KD 9216            // GEMM1 K = 36*256

typedef float f32x4 __attribute__((ext_vector_type(4)));
typedef __bf16 bf16x8 __attribute__((ext_vector_type(8)));
typedef unsigned short ushortx8 __attribute__((ext_vector_type(8)));
typedef unsigned int uintx4 __attribute__((ext_vector_type(4)));
typedef int intx4 __attribute__((ext_vector_type(4)));

__device__ __forceinline__ unsigned short f2bf(float f) {
  unsigned int u = __builtin_bit_cast(unsigned int, f);
  u += 0x7fffu + ((u >> 16) & 1u);   // round-to-nearest-even
  return (unsigned short)(u >> 16);
}
#define U2F(u) __builtin_bit_cast(float, (unsigned int)(u))

// ---------------------------------------------------------------------------
// Kernel 1 (fused prep): grid-concatenated independent phases.
__global__ void k_prep(const float* __restrict__ mem, unsigned short* __restrict__ memb,
                       const float* __restrict__ Wk, const float* __restrict__ Wp,
                       unsigned short* __restrict__ W2s, unsigned short* __restrict__ WPs,
                       const float* __restrict__ polys, float* __restrict__ outp,
                       float* __restrict__ wsp, float* __restrict__ wts) {
  const int bid = blockIdx.x;
  if (bid < 8192) {
    size_t gid = (size_t)bid * 256 + threadIdx.x;
    const float* s = mem + gid * 8;
    f32x4 a = *(const f32x4*)s, b = *(const f32x4*)(s + 4);
    bf16x8 pk;
    pk[0] = (__bf16)a.x; pk[1] = (__bf16)a.y; pk[2] = (__bf16)a.z; pk[3] = (__bf16)a.w;
    pk[4] = (__bf16)b.x; pk[5] = (__bf16)b.y; pk[6] = (__bf16)b.z; pk[7] = (__bf16)b.w;
    *(bf16x8*)(memb + gid * 8) = pk;
  } else if (bid < 9344) {
    int tid = (bid - 8192) * 256 + threadIdx.x;  // < 294912 exactly
    int o = tid & 255;
    int th = tid >> 8;                           // 0..1151  (= t>>3)
    int r = th >> 5;                             // sample slot 0..35
    int cbase = (th & 31) * 8;
    int np = r / 9;
    int kl = r - np * 9;
    int kk = kl / 3;
    int ll = kl - kk * 3;
    const float* src = Wk + (size_t)o * KD + (size_t)(np * 256 + cbase) * 9 + kk * 3 + ll;
    ushortx8 v;
#pragma unroll
    for (int j = 0; j < 8; ++j) v[j] = f2bf(src[(size_t)j * 9]);
    *(ushortx8*)(W2s + (size_t)th * 2048 + o * 8) = v;
  } else if (bid < 9376) {
    int tid = (bid - 9344) * 256 + threadIdx.x;  // < 8192 exactly
    int o = tid & 255;
    int th = tid >> 8;
    const float* src = Wp + (size_t)o * 256 + th * 8;
    ushortx8 v;
#pragma unroll
    for (int j = 0; j < 8; ++j) v[j] = f2bf(src[j]);
    *(ushortx8*)(WPs + (size_t)th * 2048 + o * 8) = v;
  } else if (bid < 10501) {
    if (!wts) return;
    int e = (bid - 9376) * 256 + threadIdx.x;    // < 288000 exactly
    int r = e / 8000;                            // 0..35
    int n = e - r * 8000;
    int s = r & 3;
    int mm = r >> 2;
    int mdiv = (mm * 11) >> 5;                   // mm/3 for mm in [0,9)
    int mmod = mm - 3 * mdiv;
    float dhx = (1.5f * (float)mdiv - 2.0f) * 0.03125f;
    float dwy = (1.5f * (float)mmod - 2.0f) * 0.03125f;
    f32x4 ca = *(const f32x4*)(polys + (size_t)n * 8);
    f32x4 cb = *(const f32x4*)(polys + (size_t)n * 8 + 4);
    float a1 = (s == 3) ? 1.0f : (float)s * 0.33333334f;
    float a2 = a1 * a1, a3 = a2 * a1;
    float v0 = ca.x * a3 + ca.y * a2 + ca.z * a1 + ca.w;
    float v1 = cb.x * a3 + cb.y * a2 + cb.z * a1 + cb.w;
    float p0 = 2.0f * v1 - 1.0f;
    float p1 = 2.0f * v0 - 1.0f;
    const float gx = (p0 + dhx + 1.0f) * 0.5f * 63.0f;  // column
    const float gy = (p1 + dwy + 1.0f) * 0.5f * 63.0f;  // row
    const float x0f = floorf(gx), y0f = floorf(gy);
    const float fx = gx - x0f, fy = gy - y0f;
    const int ix0 = (int)x0f, iy0 = (int)y0f;
    const int ix1 = ix0 + 1, iy1 = iy0 + 1;
    const float vx0 = (ix0 >= 0 && ix0 < NHW) ? 1.0f : 0.0f;
    const float vx1 = (ix1 >= 0 && ix1 < NHW) ? 1.0f : 0.0f;
    const float vy0 = (iy0 >= 0 && iy0 < NHW) ? 1.0f : 0.0f;
    const float vy1 = (iy1 >= 0 && iy1 < NHW) ? 1.0f : 0.0f;
    const float w00 = (1.0f - fy) * (1.0f - fx) * vy0 * vx0;
    const float w01 = (1.0f - fy) * fx * vy0 * vx1;
    const float w10 = fy * (1.0f - fx) * vy1 * vx0;
    const float w11 = fy * fx * vy1 * vx1;
    const int cx0 = min(max(ix0, 0), NHW - 1), cx1 = min(max(ix1, 0), NHW - 1);
    const int cy0 = min(max(iy0, 0), NHW - 1), cy1 = min(max(iy1, 0), NHW - 1);
    float* dst = wts + (size_t)e * 8;
    f32x4 wv; wv.x = w00; wv.y = w01; wv.z = w10; wv.w = w11;
    intx4 ov;
    ov.x = (cy0 * NHW + cx0) * NC; ov.y = (cy0 * NHW + cx1) * NC;
    ov.z = (cy1 * NHW + cx0) * NC; ov.w = (cy1 * NHW + cx1) * NC;
    *(f32x4*)dst = wv;
    *(intx4*)(dst + 4) = ov;
  } else {
    int n = (bid - 10501) * 256 + threadIdx.x;
    if (n >= MR) return;
    f32x4 ca = *(const f32x4*)(polys + (size_t)n * 8);
    f32x4 cb = *(const f32x4*)(polys + (size_t)n * 8 + 4);
    const float av[4] = {0.0f, 0.33333334f, 0.66666669f, 1.0f};
#pragma unroll
    for (int s = 0; s < 4; ++s) {
      float a1 = av[s], a2 = a1 * a1, a3 = a2 * a1;
      float v0 = ca.x * a3 + ca.y * a2 + ca.z * a1 + ca.w;
      float v1 = cb.x * a3 + cb.y * a2 + cb.z * a1 + cb.w;
      float pt0 = 2.0f * v1 - 1.0f;
      float pt1 = 2.0f * v0 - 1.0f;
      outp[(size_t)n * 8 + s * 2 + 0] = pt0;
      outp[(size_t)n * 8 + s * 2 + 1] = pt1;
      wsp[(size_t)n * 8 + s * 2 + 0] = pt0;
      wsp[(size_t)n * 8 + s * 2 + 1] = pt1;
    }
  }
}

// ---------------------------------------------------------------------------
// Kernel 2: fused gather + GEMM1. ROUND-17/19 VERIFIED OPTIMUM (70.5 us):
// K=4, M=64 tile, 64 KB dbuf A-LDS, ONE barrier/slot, launch_bounds(512,4),
// WTS staged via rotating 2x2KB LDS buffer.
// FINAL EXPERIMENT (T5): s_setprio(1) around the MFMA phase — the 2 resident
// blocks/CU are unsynchronized (different tiles), so while one block's waves
// run MFMA the other's are in gather; priority keeps the matrix pipe fed.
// Closed levers (measured): register prefetch (7/15/16: 64-VGPR allocator
// pin spills any persistent state); occupancy reshaping (8/9/18: 2-barrier
// loses 12-18%); VALU hand-vectorization (14: compiler already optimal).
template <bool USE_WTS>
__global__ __launch_bounds__(512, 4) void k_gemm1(
    const unsigned short* __restrict__ memb, const float* __restrict__ pts,
    const float* __restrict__ wts, const unsigned short* __restrict__ W2s,
    const float* __restrict__ bk, float* __restrict__ PART, int K) {
  __shared__ __align__(16) unsigned short Alds[2 * 2048 * 8];  // 64 KB
  __shared__ __align__(16) float Wlds[2][512];                 // 2 x 2 KB

  const int bid = blockIdx.x;
  const int x = bid & 7;
  const int kk8 = (bid >> 3) % K;
  const int j = bid / (8 * K);
  const int t = x + 8 * j;
  if (t >= 125) return;
  const int tt = 16 * x - ((x > 5) ? (x - 5) : 0) + j;   // contiguous tile id
  const int nsl = 36 / K;
  const int r0 = kk8 * nsl;

  const int tid = threadIdx.x;
  const int n0 = tt * 64;
  const int lane = tid & 63;
  const int wave = tid >> 6;   // 0..7
  const int lr = lane & 15;
  const int ksub = lane >> 4;
  const int o0 = wave * 32;

  const int gchunk = tid & 31;
  const int gm0 = tid >> 5;    // 0..15 ; tasks handle rows gm0+16*task

  size_t boff[4];
  int nrow[4];
#pragma unroll
  for (int task = 0; task < 4; ++task) {
    nrow[task] = n0 + gm0 + 16 * task;
    boff[task] = (size_t)(nrow[task] / NQ) * (NHW * NHW * NC);
  }

  f32x4 acc[4][2] = {};

  // prologue: stage slot r0's WTS slice (2 KB) into Wlds[0]
  if (USE_WTS) {
    if (tid < 128) {
      f32x4 v = *(const f32x4*)(wts + ((size_t)r0 * 8000 + n0) * 8 + tid * 4);
      *(f32x4*)(&Wlds[0][tid * 4]) = v;
    }
    __syncthreads();
  }

  for (int r = r0; r < r0 + nsl; ++r) {
    const int lbase = ((r - r0) & 1) * 2048;   // A-LDS buffer select
    const int cur = (r - r0) & 1;              // WTS LDS buffer select
    const int nbuf = cur ^ 1;
    const int rn = (r + 1 < 35) ? (r + 1) : 35;  // next-slot stage (clamped;
                                                 // final iteration's is unused)
    float dhx = 0.0f, dwy = 0.0f;
    int s = 0;
    if (!USE_WTS) {
      s = r & 3;
      const int mm = r >> 2;
      const int mdiv = (mm * 11) >> 5;
      const int mmod = mm - 3 * mdiv;
      dhx = (1.5f * (float)mdiv - 2.0f) * 0.03125f;
      dwy = (1.5f * (float)mmod - 2.0f) * 0.03125f;
    } else {
      // stage slot r+1's WTS slice early: global load overlaps the 4 task
      // bodies; ds_write lands before this slot's barrier.
      if (tid < 128) {
        f32x4 v = *(const f32x4*)(wts + ((size_t)rn * 8000 + n0) * 8 + tid * 4);
        *(f32x4*)(&Wlds[nbuf][tid * 4]) = v;
      }
    }
#pragma unroll 2
    for (int task = 0; task < 4; ++task) {
      const int m = gm0 + task * 16;
      const int n = nrow[task];
      float w00, w01, w10, w11;
      int o00, o01, o10, o11;
      if (USE_WTS) {
        const float* we = &Wlds[cur][(gm0 + 16 * task) * 8];
        f32x4 wv = *(const f32x4*)we;
        intx4 ov = *(const intx4*)(we + 4);
        w00 = wv.x; w01 = wv.y; w10 = wv.z; w11 = wv.w;
        o00 = ov.x; o01 = ov.y; o10 = ov.z; o11 = ov.w;
      } else {
        const float p0 = pts[(size_t)n * 8 + s * 2 + 0];
        const float p1 = pts[(size_t)n * 8 + s * 2 + 1];
        const float gx = (p0 + dhx + 1.0f) * 0.5f * 63.0f;  // column
        const float gy = (p1 + dwy + 1.0f) * 0.5f * 63.0f;  // row
        const float x0f = floorf(gx), y0f = floorf(gy);
        const float fx = gx - x0f, fy = gy - y0f;
        const int ix0 = (int)x0f, iy0 = (int)y0f;
        const int ix1 = ix0 + 1, iy1 = iy0 + 1;
        const float vx0 = (ix0 >= 0 && ix0 < NHW) ? 1.0f : 0.0f;
        const float vx1 = (ix1 >= 0 && ix1 < NHW) ? 1.0f : 0.0f;
        const float vy0 = (iy0 >= 0 && iy0 < NHW) ? 1.0f : 0.0f;
        const float vy1 = (iy1 >= 0 && iy1 < NHW) ? 1.0f : 0.0f;
        w00 = (1.0f - fy) * (1.0f - fx) * vy0 * vx0;
        w01 = (1.0f - fy) * fx * vy0 * vx1;
        w10 = fy * (1.0f - fx) * vy1 * vx0;
        w11 = fy * fx * vy1 * vx1;
        const int cx0 = min(max(ix0, 0), NHW - 1), cx1 = min(max(ix1, 0), NHW - 1);
        const int cy0 = min(max(iy0, 0), NHW - 1), cy1 = min(max(iy1, 0), NHW - 1);
        o00 = (cy0 * NHW + cx0) * NC; o01 = (cy0 * NHW + cx1) * NC;
        o10 = (cy1 * NHW + cx0) * NC; o11 = (cy1 * NHW + cx1) * NC;
      }
      const unsigned short* mb = memb + boff[task] + gchunk * 8;
      uintx4 u00 = *(const uintx4*)(mb + o00);
      uintx4 u01 = *(const uintx4*)(mb + o01);
      uintx4 u10 = *(const uintx4*)(mb + o10);
      uintx4 u11 = *(const uintx4*)(mb + o11);
      // expand: word w holds elems {2w (lo), 2w+1 (hi)}; ra <- elems 0..3,
      // rb <- elems 4..7
      f32x4 a00, b00, a01, b01, a10, b10, a11, b11;
      a00.x = U2F(u00.x << 16); a00.y = U2F(u00.x & 0xFFFF0000u);
      a00.z = U2F(u00.y << 16); a00.w = U2F(u00.y & 0xFFFF0000u);
      b00.x = U2F(u00.z << 16); b00.y = U2F(u00.z & 0xFFFF0000u);
      b00.z = U2F(u00.w << 16); b00.w = U2F(u00.w & 0xFFFF0000u);
      a01.x = U2F(u01.x << 16); a01.y = U2F(u01.x & 0xFFFF0000u);
      a01.z = U2F(u01.y << 16); a01.w = U2F(u01.y & 0xFFFF0000u);
      b01.x = U2F(u01.z << 16); b01.y = U2F(u01.z & 0xFFFF0000u);
      b01.z = U2F(u01.w << 16); b01.w = U2F(u01.w & 0xFFFF0000u);
      a10.x = U2F(u10.x << 16); a10.y = U2F(u10.x & 0xFFFF0000u);
      a10.z = U2F(u10.y << 16); a10.w = U2F(u10.y & 0xFFFF0000u);
      b10.x = U2F(u10.z << 16); b10.y = U2F(u10.z & 0xFFFF0000u);
      b10.z = U2F(u10.w << 16); b10.w = U2F(u10.w & 0xFFFF0000u);
      a11.x = U2F(u11.x << 16); a11.y = U2F(u11.x & 0xFFFF0000u);
      a11.z = U2F(u11.y << 16); a11.w = U2F(u11.y & 0xFFFF0000u);
      b11.x = U2F(u11.z << 16); b11.y = U2F(u11.z & 0xFFFF0000u);
      b11.z = U2F(u11.w << 16); b11.w = U2F(u11.w & 0xFFFF0000u);
      f32x4 ra = a00 * w00 + a01 * w01 + a10 * w10 + a11 * w11;
      f32x4 rb = b00 * w00 + b01 * w01 + b10 * w10 + b11 * w11;
      bf16x8 pk;
      pk[0] = (__bf16)ra.x; pk[1] = (__bf16)ra.y;
      pk[2] = (__bf16)ra.z; pk[3] = (__bf16)ra.w;
      pk[4] = (__bf16)rb.x; pk[5] = (__bf16)rb.y;
      pk[6] = (__bf16)rb.z; pk[7] = (__bf16)rb.w;
      const int slot = lbase + gchunk * 64 + (m ^ (gchunk & 15));
      *(bf16x8*)(Alds + slot * 8) = pk;
    }
    __syncthreads();
    const size_t rbase = (size_t)r * 32;
    __builtin_amdgcn_s_setprio(1);   // favor MFMA-phase waves over the other
                                     // resident block's gather waves (T5)
#pragma unroll
    for (int kstep = 0; kstep < 8; ++kstep) {
      const int chunk = kstep * 4 + ksub;
      const unsigned short* bp = W2s + (rbase + chunk) * 2048 + (o0 + lr) * 8;
      ushortx8 ub0 = *(const ushortx8*)bp;
      ushortx8 ub1 = *(const ushortx8*)(bp + 128);
      bf16x8 fb0 = __builtin_bit_cast(bf16x8, ub0);
      bf16x8 fb1 = __builtin_bit_cast(bf16x8, ub1);
#pragma unroll
      for (int mf = 0; mf < 4; ++mf) {
        const int sa = lbase + chunk * 64 + ((mf * 16 + lr) ^ (chunk & 15));
        ushortx8 ua = *(const ushortx8*)(Alds + sa * 8);
        bf16x8 fa = __builtin_bit_cast(bf16x8, ua);
        acc[mf][0] = __builtin_amdgcn_mfma_f32_16x16x32_bf16(fa, fb0, acc[mf][0], 0, 0, 0);
        acc[mf][1] = __builtin_amdgcn_mfma_f32_16x16x32_bf16(fa, fb1, acc[mf][1], 0, 0, 0);
      }
    }
    __builtin_amdgcn_s_setprio(0);
  }
  // epilogue: fp32 partials. C/D: col=lane&15, row=(lane>>4)*4+reg
  float* dst = PART + (size_t)kk8 * (MR * NC);
#pragma unroll
  for (int mf = 0; mf < 4; ++mf)
#pragma unroll
    for (int nf = 0; nf < 2; ++nf) {
      const int o = o0 + nf * 16 + lr;
#pragma unroll
      for (int reg = 0; reg < 4; ++reg) {
        const int mrow = mf * 16 + ksub * 4 + reg;
        dst[(size_t)(n0 + mrow) * 256 + o] = acc[mf][nf][reg];
      }
    }
}

// ---------------------------------------------------------------------------
// Kernel 3: fused reduce + GEMM2 (16-row tiles).
// A-fragment built in-register: sum 4 PART slices, +bk, relu, native bf16 cast
// (== k_red's f2bf, verified). Same sum order k=0..3 as k_red => bit-identical.
__global__ __launch_bounds__(256) void k_gemm2(
    const float* __restrict__ PART, const float* __restrict__ bk,
    const unsigned short* __restrict__ WPs, const float* __restrict__ bp,
    float* __restrict__ outc) {
  const int tid = threadIdx.x;
  const int n0 = blockIdx.x * 16;
  const int lane = tid & 63;
  const int wave = tid >> 6;  // 0..3
  const int lr = lane & 15;
  const int ksub = lane >> 4;
  const int o0 = wave * 64;
  f32x4 acc[4] = {};
#pragma unroll
  for (int kstep = 0; kstep < 8; ++kstep) {
    const int t0 = kstep * 32 + ksub * 8;
    const float* base = PART + (size_t)(n0 + lr) * 256 + t0;
    f32x4 s0 = *(const f32x4*)base;
    f32x4 s1 = *(const f32x4*)(base + 4);
#pragma unroll
    for (int k = 1; k < 4; ++k) {
      const float* pk_ = base + (size_t)k * (MR * NC);
      s0 += *(const f32x4*)pk_;
      s1 += *(const f32x4*)(pk_ + 4);
    }
    s0 += *(const f32x4*)(bk + t0);
    s1 += *(const f32x4*)(bk + t0 + 4);
    bf16x8 fa;
#pragma unroll
    for (int e = 0; e < 4; ++e) {
      float v0 = s0[e] > 0.0f ? s0[e] : 0.0f;
      float v1 = s1[e] > 0.0f ? s1[e] : 0.0f;
      fa[e] = (__bf16)v0;
      fa[e + 4] = (__bf16)v1;
    }
    const int chunk = kstep * 4 + ksub;
#pragma unroll
    for (int nf = 0; nf < 4; ++nf) {
      ushortx8 ub = *(const ushortx8*)(WPs + (size_t)chunk * 2048 + (o0 + nf * 16 + lr) * 8);
      bf16x8 fb = __builtin_bit_cast(bf16x8, ub);
      acc[nf] = __builtin_amdgcn_mfma_f32_16x16x32_bf16(fa, fb, acc[nf], 0, 0, 0);
    }
  }
#pragma unroll
  for (int nf = 0; nf < 4; ++nf) {
    const int o = o0 + nf * 16 + lr;
    const float bpo = bp[o];
#pragma unroll
    for (int reg = 0; reg < 4; ++reg) {
      const int mrow = ksub * 4 + reg;
      outc[(size_t)(n0 + mrow) * 256 + o] = acc[nf][reg] + bpo;
    }
  }
}

// ---------------------------------------------------------------------------
extern "C" void kernel_launch(void* const* d_in, const int* in_sizes, int n_in,
                              void* d_out, int out_size, void* d_ws, size_t ws_size,
                              hipStream_t stream) {
  (void)in_sizes; (void)n_in; (void)out_size;
  const float* polys = (const float*)d_in[1];
  const float* mem   = (const float*)d_in[2];
  const float* Wk    = (const float*)d_in[4];
  const float* bk    = (const float*)d_in[5];
  const float* Wp    = (const float*)d_in[6];
  const float* bp    = (const float*)d_in[7];
  float* out = (float*)d_out;
  float* out_pts = out + (size_t)MR * NC;   // second output: points

  // ws layout: base block, then [WTS?] + MEMB + PART (K=4)
  unsigned short* W2s = (unsigned short*)d_ws;                       // 4,718,592 B
  unsigned short* WPs = (unsigned short*)((char*)d_ws + 4718592);    //   131,072 B
  float*          PTS = (float*)((char*)d_ws + 4849664);             //   256,000 B
  const size_t BASE_END = 9201664;
  const size_t WTS_SZ  = 9216000ull;      // 288000 * 32 B
  const size_t MEMB_SZ = 33554432ull;     // 16*4096*256 bf16
  const size_t PART_SZ = 8192000ull;      // 8000*256 fp32 per split
  const int K = 4;

  bool use_wts = (ws_size >= BASE_END + WTS_SZ + MEMB_SZ + 4 * PART_SZ);
  size_t memb_off = use_wts ? (BASE_END + WTS_SZ) : BASE_END;
  float*          WTS  = use_wts ? (float*)((char*)d_ws + BASE_END) : nullptr;
  unsigned short* MEMB = (unsigned short*)((char*)d_ws + memb_off);
  float*          PART = (float*)((char*)d_ws + memb_off + MEMB_SZ);

  hipLaunchKernelGGL(k_prep, dim3(10533), dim3(256), 0, stream,
                     mem, MEMB, Wk, Wp, W2s, WPs, polys, out_pts, PTS, WTS);
  if (use_wts)
    hipLaunchKernelGGL(k_gemm1<true>, dim3(128 * K), dim3(512), 0, stream,
                       MEMB, PTS, WTS, W2s, bk, PART, K);
  else
    hipLaunchKernelGGL(k_gemm1<false>, dim3(128 * K), dim3(512), 0, stream,
                       MEMB, PTS, WTS, W2s, bk, PART, K);
  hipLaunchKernelGGL(k_gemm2, dim3(500), dim3(256), 0, stream, PART, bk, WPs, bp, out);
}